// Round 16
// baseline (345.870 us; speedup 1.0000x reference)
//
#include <hip/hip_runtime.h>

#define ND 4
#define ED 128
#define KCODES 4096
#define NTOK 16384          // B*S
#define HID 512
#define NTOT (ND*ED*NTOK)   // 8388608

#define MARGIN 2.0e-3f
#define FLAG_CAP 16384

typedef __attribute__((ext_vector_type(8))) short short8v;
typedef __attribute__((ext_vector_type(4))) float float4v;

#define GLDS16(g, l) __builtin_amdgcn_global_load_lds( \
    (const __attribute__((address_space(1))) unsigned int*)(g), \
    (__attribute__((address_space(3))) unsigned int*)(l), 16, 0, 0)

__device__ __forceinline__ unsigned short bf16h(float x) {
    unsigned u = __float_as_uint(x);
    return (unsigned short)((u + 0x7fffu + ((u >> 16) & 1u)) >> 16);
}
__device__ __forceinline__ float bf16f(unsigned short h) {
    return __uint_as_float(((unsigned)h) << 16);
}

// Fused: exact e2 (serial asc-e mul/add, bit-matches ref), B hi/lo split into
// swizzled fragment-order chunks, flag_cnt zero. Grid (256 tiles x 16 codes, 4 d).
__global__ __launch_bounds__(256) void e2split_kernel(const float* __restrict__ emb,
        float* __restrict__ e2g,
        unsigned short* __restrict__ bth2, unsigned short* __restrict__ btl2,
        int* __restrict__ flag_cnt) {
    __shared__ float Tf[128][17];
    const int tile = blockIdx.x;      // 16-code tile
    const int d    = blockIdx.y;
    const int tid  = threadIdx.x;
    const int k0   = tile * 16;
    if (tile == 0 && d == 0 && tid == 0) *flag_cnt = 0;
    {
        int e = tid >> 1, half = tid & 1;
        const float* src = emb + ((size_t)d * ED + e) * KCODES + k0 + half * 8;
        float4 v0 = *(const float4*)(src);
        float4 v1 = *(const float4*)(src + 4);
        float* dst = &Tf[e][half * 8];
        dst[0] = v0.x; dst[1] = v0.y; dst[2] = v0.z; dst[3] = v0.w;
        dst[4] = v1.x; dst[5] = v1.y; dst[6] = v1.z; dst[7] = v1.w;
    }
    __syncthreads();
    if (tid < 16) {
        float s = 0.f;
        for (int e = 0; e < ED; ++e) {
            float v = Tf[e][tid];
            s = __fadd_rn(s, __fmul_rn(v, v));
        }
        e2g[d * KCODES + k0 + tid] = s;
    }
    // 512 chunks: c<256 = hi, else lo; cc = code*16 + g'; g = g'^code; e0 = g*8
    #pragma unroll
    for (int q = 0; q < 2; ++q) {
        int c    = q * 256 + tid;
        int arr  = c >> 8;
        int cc   = c & 255;
        int code = cc >> 4;
        int gp   = cc & 15;
        int e0   = (gp ^ code) * 8;
        short8v v;
        #pragma unroll
        for (int j = 0; j < 8; ++j) {
            float x = Tf[e0 + j][code];
            unsigned short hb = bf16h(x);
            v[j] = arr ? (short)bf16h(x - bf16f(hb)) : (short)hb;
        }
        unsigned short* dst = (arr ? btl2 : bth2) + ((size_t)(d * 256 + tile) * 256 + cc) * 8;
        *(short8v*)dst = v;
    }
}

// MFMA bf16x3 argmin, K-split (4 waves = 2 token-groups x 2 code-halves),
// global_load_lds staging, merged accumulator. __launch_bounds__(256,2):
// min-waves=2 lets the backend settle at ~104-124 VGPR with NO spill (r12
// evidence); VGPR in (64,128] + 40KB LDS still yields 4 blocks/CU at runtime.
// (min-waves=4 or waves_per_eu(4,4) made the heuristic target 8 waves/EU and
// spill 50 regs — r13/r14/r15 evidence.)
__global__ __launch_bounds__(256, 2)
void argmin_mfma_kernel(const float* __restrict__ in,
        const unsigned short* __restrict__ bth2, const unsigned short* __restrict__ btl2,
        const float* __restrict__ e2g, int* __restrict__ lat,
        int* __restrict__ flag_cnt, int* __restrict__ flag_list) {
    __shared__ __align__(16) unsigned short Bst[20480];  // 40 KB (32 KB used + pad)

    // XCD-aware decode: blocks on one XCD share one d
    const int l   = blockIdx.x;           // 0..1023
    const int r8  = l & 7;
    const int d   = r8 >> 1;
    const int tI  = 2 * (l >> 3) + (r8 & 1);   // 0..255
    const int t0  = tI * 64;

    const int tid  = threadIdx.x;
    const int wid  = tid >> 6;
    const int lane = tid & 63;
    const int l15  = lane & 15;
    const int lk8  = lane >> 4;     // 0..3
    const int tg   = wid & 1;       // token group (32 tokens)
    const int h    = wid >> 1;      // code half

    // A fragments: rows t0 + tg*32 + rt*16 + l15, e = ks*32 + lk8*8 + j
    short8v ahf[2][4], alf[2][4];
    #pragma unroll
    for (int rt = 0; rt < 2; ++rt) {
        const float* ap = in + (size_t)(t0 + tg * 32 + rt * 16 + l15) * HID + d * ED + lk8 * 8;
        #pragma unroll
        for (int ks = 0; ks < 4; ++ks) {
            float4 v0 = *(const float4*)(ap + ks * 32);
            float4 v1 = *(const float4*)(ap + ks * 32 + 4);
            float vv[8] = {v0.x, v0.y, v0.z, v0.w, v1.x, v1.y, v1.z, v1.w};
            short8v hv, lv;
            #pragma unroll
            for (int j = 0; j < 8; ++j) {
                unsigned short hb = bf16h(vv[j]);
                hv[j] = (short)hb;
                lv[j] = (short)bf16h(vv[j] - bf16f(hb));
            }
            ahf[rt][ks] = hv; alf[rt][ks] = lv;
        }
    }

    float b1[2][4], b2[2][4];
    int   bk[2][4];
    #pragma unroll
    for (int rt = 0; rt < 2; ++rt)
        #pragma unroll
        for (int r = 0; r < 4; ++r) { b1[rt][r] = 3.0e38f; b2[rt][r] = 3.0e38f; bk[rt][r] = 0; }

    char* lb = (char*)Bst;
    const int ldsW = (tid >> 6) * 1024;     // wave-uniform lane-block base

    for (int j = 0; j < 64; ++j) {
        __syncthreads();                    // iter j-1 readers done
        // stage sub-tiles 2j, 2j+1 (both halves, hi+lo): 8 x glds16 per lane
        #pragma unroll
        for (int sub = 0; sub < 2; ++sub) {
            const int ktL = 2 * j + sub;
            #pragma unroll
            for (int q4 = 0; q4 < 4; ++q4) {
                const unsigned short* src = (q4 & 1 ? btl2 : bth2) +
                    ((size_t)(d * 256 + (q4 >> 1) * 128 + ktL) * 256 + tid) * 8;
                GLDS16(src, lb + sub * 16384 + q4 * 4096 + ldsW);
            }
        }
        __syncthreads();                    // barrier drains vmcnt -> data visible

        #pragma unroll
        for (int sub = 0; sub < 2; ++sub) {
            const int codev = h * 2048 + (2 * j + sub) * 16 + l15;
            const float e2v = e2g[d * KCODES + codev];
            const int hb0 = sub * 16384 + h * 8192;
            float4v acc[2] = {{0,0,0,0},{0,0,0,0}};
            #pragma unroll
            for (int ks = 0; ks < 4; ++ks) {
                const int gswz = (ks * 4 + lk8) ^ l15;
                short8v bh = *(const short8v*)(lb + hb0 + (l15 * 16 + gswz) * 16);
                short8v bl = *(const short8v*)(lb + hb0 + 4096 + (l15 * 16 + gswz) * 16);
                acc[0] = __builtin_amdgcn_mfma_f32_16x16x32_bf16(ahf[0][ks], bh, acc[0], 0, 0, 0);
                acc[1] = __builtin_amdgcn_mfma_f32_16x16x32_bf16(ahf[1][ks], bh, acc[1], 0, 0, 0);
                acc[0] = __builtin_amdgcn_mfma_f32_16x16x32_bf16(alf[0][ks], bh, acc[0], 0, 0, 0);
                acc[1] = __builtin_amdgcn_mfma_f32_16x16x32_bf16(alf[1][ks], bh, acc[1], 0, 0, 0);
                acc[0] = __builtin_amdgcn_mfma_f32_16x16x32_bf16(ahf[0][ks], bl, acc[0], 0, 0, 0);
                acc[1] = __builtin_amdgcn_mfma_f32_16x16x32_bf16(ahf[1][ks], bl, acc[1], 0, 0, 0);
            }
            #pragma unroll
            for (int rt = 0; rt < 2; ++rt) {
                #pragma unroll
                for (int r = 0; r < 4; ++r) {
                    float dv = __fmaf_rn(-2.0f, acc[rt][r], e2v);
                    if (dv < b1[rt][r]) { b2[rt][r] = b1[rt][r]; b1[rt][r] = dv; bk[rt][r] = codev; }
                    else if (dv < b2[rt][r]) { b2[rt][r] = dv; }
                }
            }
        }
    }

    // butterfly merge over the 16 column-lanes, tie -> lowest k
    #pragma unroll
    for (int m = 1; m <= 8; m <<= 1) {
        #pragma unroll
        for (int rt = 0; rt < 2; ++rt) {
            #pragma unroll
            for (int r = 0; r < 4; ++r) {
                float od = __shfl_xor(b1[rt][r], m, 64);
                float o2 = __shfl_xor(b2[rt][r], m, 64);
                int   ok = __shfl_xor(bk[rt][r], m, 64);
                if (od < b1[rt][r] || (od == b1[rt][r] && ok < bk[rt][r])) {
                    b2[rt][r] = fminf(b1[rt][r], o2);
                    b1[rt][r] = od;
                    bk[rt][r] = ok;
                } else {
                    b2[rt][r] = fminf(b2[rt][r], od);
                }
            }
        }
    }
    __syncthreads();    // Bst no longer needed; overlay merge arrays
    float* mb1 = (float*)Bst;         // [128]
    float* mb2 = mb1 + 128;           // [128]
    int*   mbk = (int*)(mb1 + 256);   // [128]
    if (l15 == 0) {
        #pragma unroll
        for (int rt = 0; rt < 2; ++rt) {
            #pragma unroll
            for (int r = 0; r < 4; ++r) {
                int tok = tg * 32 + rt * 16 + lk8 * 4 + r;   // 0..63
                mb1[h * 64 + tok] = b1[rt][r];
                mb2[h * 64 + tok] = b2[rt][r];
                mbk[h * 64 + tok] = bk[rt][r];
            }
        }
    }
    __syncthreads();
    if (tid < 64) {
        float a1 = mb1[tid],      a2 = mb2[tid];      int ak = mbk[tid];
        float c1 = mb1[64 + tid], c2 = mb2[64 + tid]; int ck = mbk[64 + tid];
        float B1, B2; int K;
        if (a1 < c1 || (a1 == c1 && ak < ck)) { B1 = a1; K = ak; B2 = fminf(a2, c1); }
        else                                  { B1 = c1; K = ck; B2 = fminf(c2, a1); }
        int tok = d * NTOK + t0 + tid;
        lat[tok] = K;
        if (B2 - B1 < MARGIN) {
            int slot = atomicAdd(flag_cnt, 1);
            if (slot < FLAG_CAP) flag_list[slot] = tok;
        }
    }
}

// Exact repair, bit-matching verified ref semantics (x2 computed in-kernel).
__global__ __launch_bounds__(256) void repair_kernel(const float* __restrict__ in,
        const float* __restrict__ emb, const float* __restrict__ e2g,
        const int* __restrict__ flag_cnt, const int* __restrict__ flag_list,
        int* __restrict__ lat) {
    __shared__ float xs[ED];
    __shared__ float rd[256];
    __shared__ int   rk[256];
    int n = *flag_cnt;
    if (n > FLAG_CAP) n = FLAG_CAP;
    for (int idx = blockIdx.x; idx < n; idx += gridDim.x) {
        int tok = flag_list[idx];
        int d = tok >> 14;               // tok = d*NTOK + t
        int t = tok & (NTOK - 1);
        __syncthreads();
        if (threadIdx.x < ED) xs[threadIdx.x] = in[(size_t)t * HID + d * ED + threadIdx.x];
        __syncthreads();
        float x2v = 0.f;                 // strict serial, matches ref
        for (int e = 0; e < ED; ++e) x2v = __fadd_rn(x2v, __fmul_rn(xs[e], xs[e]));
        const float* __restrict__ embd = emb + (size_t)d * ED * KCODES;
        float bd = 3.0e38f; int bkk = 0;
        for (int j = 0; j < 16; ++j) {
            int k = threadIdx.x + j * 256;      // ascending k per thread
            float acc = 0.f;
            #pragma unroll 16
            for (int e = 0; e < ED; ++e)
                acc = __fmaf_rn(xs[e], embd[(size_t)e * KCODES + k], acc);
            float dist = __fsub_rn(__fadd_rn(x2v, e2g[d * KCODES + k]),
                                   __fmul_rn(2.0f, acc));
            if (dist < bd) { bd = dist; bkk = k; }
        }
        rd[threadIdx.x] = bd; rk[threadIdx.x] = bkk;
        __syncthreads();
        for (int w = 128; w > 0; w >>= 1) {
            if (threadIdx.x < w) {
                float od = rd[threadIdx.x + w]; int ok = rk[threadIdx.x + w];
                if (od < rd[threadIdx.x] || (od == rd[threadIdx.x] && ok < rk[threadIdx.x])) {
                    rd[threadIdx.x] = od; rk[threadIdx.x] = ok;
                }
            }
            __syncthreads();
        }
        if (threadIdx.x == 0) lat[tok] = rk[0];
    }
}

// out[n] = fl(fl(x + e) - x), n = (d,e,t); per-block partials of (x - e)^2
__global__ __launch_bounds__(256) void gather_kernel(const float* __restrict__ in,
        const float* __restrict__ emb, const int* __restrict__ lat,
        float* __restrict__ out, float* __restrict__ partial) {
    int tid  = threadIdx.x;
    int base = blockIdx.x * 1024 + tid * 4;
    int d = base >> 21;
    int e = (base >> 14) & 127;
    int t = base & (NTOK - 1);
    const int4 kk = *(const int4*)(lat + d * NTOK + t);
    const float* __restrict__ row = emb + ((size_t)(d * ED + e)) * KCODES;
    float enc[4];
    enc[0] = row[kk.x]; enc[1] = row[kk.y]; enc[2] = row[kk.z]; enc[3] = row[kk.w];
    const float4 x = *(const float4*)(in + base);
    const float xv[4] = {x.x, x.y, x.z, x.w};
    float4 ov; float* o = (float*)&ov;
    float s = 0.f;
    #pragma unroll
    for (int i = 0; i < 4; ++i) {
        o[i] = __fsub_rn(__fadd_rn(xv[i], enc[i]), xv[i]);
        float df = xv[i] - enc[i];
        s = __fmaf_rn(df, df, s);
    }
    *(float4*)(out + base) = ov;
    #pragma unroll
    for (int off = 32; off > 0; off >>= 1) s += __shfl_down(s, off, 64);
    __shared__ float wsum[4];
    if ((tid & 63) == 0) wsum[tid >> 6] = s;
    __syncthreads();
    if (tid == 0) partial[blockIdx.x] = wsum[0] + wsum[1] + wsum[2] + wsum[3];
}

__global__ __launch_bounds__(256) void finalize_kernel(const float* __restrict__ partial,
                                                       float* __restrict__ out_tail) {
    __shared__ double sh[256];
    double s = 0.0;
    for (int i = threadIdx.x; i < 8192; i += 256) s += (double)partial[i];
    sh[threadIdx.x] = s;
    __syncthreads();
    for (int w = 128; w > 0; w >>= 1) {
        if (threadIdx.x < w) sh[threadIdx.x] += sh[threadIdx.x + w];
        __syncthreads();
    }
    if (threadIdx.x == 0) {
        double mean = sh[0] / (double)NTOT;
        out_tail[0] = (float)(0.25 * mean);   // loss
        out_tail[1] = (float)mean;            // commit_loss
        ((int*)out_tail)[2] = 0;              // kl (int32 0 == fp32 0.0 bits)
    }
}

extern "C" void kernel_launch(void* const* d_in, const int* in_sizes, int n_in,
                              void* d_out, int out_size, void* d_ws, size_t ws_size,
                              hipStream_t stream) {
    const float* in  = (const float*)d_in[0];
    const float* emb = (const float*)d_in[1];
    float* out = (float*)d_out;
    char* ws = (char*)d_ws;

    int*   lat       = (int*)ws;                         // 256 KB
    float* e2g       = (float*)(ws + 262144);            // 64 KB
    float* partial   = (float*)(ws + 327680);            // 32 KB
    int*   flag_cnt  = (int*)(ws + 360448);              // 4 B
    int*   flag_list = (int*)(ws + 360452);              // 64 KB
    unsigned short* bth2 = (unsigned short*)(ws + (1 << 20));             // 4 MB
    unsigned short* btl2 = (unsigned short*)(ws + (1 << 20) + 4194304);   // 4 MB

    hipLaunchKernelGGL(e2split_kernel, dim3(256, 4), dim3(256), 0, stream,
                       emb, e2g, bth2, btl2, flag_cnt);
    hipLaunchKernelGGL(argmin_mfma_kernel, dim3(1024), dim3(256), 0, stream,
                       in, bth2, btl2, e2g, lat, flag_cnt, flag_list);
    hipLaunchKernelGGL(repair_kernel, dim3(64), dim3(256), 0, stream,
                       in, emb, e2g, flag_cnt, flag_list, lat);
    hipLaunchKernelGGL(gather_kernel, dim3(NTOT / 1024), dim3(256), 0, stream,
                       in, emb, lat, out, partial);
    hipLaunchKernelGGL(finalize_kernel, dim3(1), dim3(256), 0, stream, partial, out + NTOT);
}

// Round 17
// 339.988 us; speedup vs baseline: 1.0173x; 1.0173x over previous
//
#include <hip/hip_runtime.h>

#define ND 4
#define ED 128
#define KCODES 4096
#define NTOK 16384          // B*S
#define HID 512
#define NTOT (ND*ED*NTOK)   // 8388608

#define MARGIN 2.0e-3f
#define FLAG_CAP 16384

typedef __attribute__((ext_vector_type(8))) short short8v;
typedef __attribute__((ext_vector_type(4))) float float4v;

#define GLDS16(g, l) __builtin_amdgcn_global_load_lds( \
    (const __attribute__((address_space(1))) unsigned int*)(g), \
    (__attribute__((address_space(3))) unsigned int*)(l), 16, 0, 0)

__device__ __forceinline__ unsigned short bf16h(float x) {
    unsigned u = __float_as_uint(x);
    return (unsigned short)((u + 0x7fffu + ((u >> 16) & 1u)) >> 16);
}
__device__ __forceinline__ float bf16f(unsigned short h) {
    return __uint_as_float(((unsigned)h) << 16);
}

// Fused: exact e2 (serial asc-e mul/add, bit-matches ref), B hi/lo split into
// swizzled fragment-order chunks, flag_cnt zero. Grid (256 tiles x 16 codes, 4 d).
__global__ __launch_bounds__(256) void e2split_kernel(const float* __restrict__ emb,
        float* __restrict__ e2g,
        unsigned short* __restrict__ bth2, unsigned short* __restrict__ btl2,
        int* __restrict__ flag_cnt) {
    __shared__ float Tf[128][17];
    const int tile = blockIdx.x;      // 16-code tile
    const int d    = blockIdx.y;
    const int tid  = threadIdx.x;
    const int k0   = tile * 16;
    if (tile == 0 && d == 0 && tid == 0) *flag_cnt = 0;
    {
        int e = tid >> 1, half = tid & 1;
        const float* src = emb + ((size_t)d * ED + e) * KCODES + k0 + half * 8;
        float4 v0 = *(const float4*)(src);
        float4 v1 = *(const float4*)(src + 4);
        float* dst = &Tf[e][half * 8];
        dst[0] = v0.x; dst[1] = v0.y; dst[2] = v0.z; dst[3] = v0.w;
        dst[4] = v1.x; dst[5] = v1.y; dst[6] = v1.z; dst[7] = v1.w;
    }
    __syncthreads();
    if (tid < 16) {
        float s = 0.f;
        for (int e = 0; e < ED; ++e) {
            float v = Tf[e][tid];
            s = __fadd_rn(s, __fmul_rn(v, v));
        }
        e2g[d * KCODES + k0 + tid] = s;
    }
    // 512 chunks: c<256 = hi, else lo; cc = code*16 + g'; g = g'^code; e0 = g*8
    #pragma unroll
    for (int q = 0; q < 2; ++q) {
        int c    = q * 256 + tid;
        int arr  = c >> 8;
        int cc   = c & 255;
        int code = cc >> 4;
        int gp   = cc & 15;
        int e0   = (gp ^ code) * 8;
        short8v v;
        #pragma unroll
        for (int j = 0; j < 8; ++j) {
            float x = Tf[e0 + j][code];
            unsigned short hb = bf16h(x);
            v[j] = arr ? (short)bf16h(x - bf16f(hb)) : (short)hb;
        }
        unsigned short* dst = (arr ? btl2 : bth2) + ((size_t)(d * 256 + tile) * 256 + cc) * 8;
        *(short8v*)dst = v;
    }
}

// MFMA bf16x3 argmin, K-split (4 waves = 2 token-groups x 2 code-halves).
// 2-phase double-buffered pipeline (T3 minimum recipe): STAGE(buf[p^1], s+1)
// -> compute buf[p] -> vmcnt(0) -> s_barrier. One barrier per 16-code tile;
// next tile's L2 loads fly under the current tile's 24-MFMA cluster.
__global__ __launch_bounds__(256, 2)
void argmin_mfma_kernel(const float* __restrict__ in,
        const unsigned short* __restrict__ bth2, const unsigned short* __restrict__ btl2,
        const float* __restrict__ e2g, int* __restrict__ lat,
        int* __restrict__ flag_cnt, int* __restrict__ flag_list) {
    __shared__ __align__(16) unsigned short Bst[16384];  // 32 KB = 2 x 16 KB dbuf

    // XCD-aware decode: blocks on one XCD share one d
    const int l   = blockIdx.x;           // 0..1023
    const int r8  = l & 7;
    const int d   = r8 >> 1;
    const int tI  = 2 * (l >> 3) + (r8 & 1);   // 0..255
    const int t0  = tI * 64;

    const int tid  = threadIdx.x;
    const int wid  = tid >> 6;
    const int lane = tid & 63;
    const int l15  = lane & 15;
    const int lk8  = lane >> 4;     // 0..3
    const int tg   = wid & 1;       // token group (32 tokens)
    const int h    = wid >> 1;      // code half

    // A fragments: rows t0 + tg*32 + rt*16 + l15, e = ks*32 + lk8*8 + j
    short8v ahf[2][4], alf[2][4];
    #pragma unroll
    for (int rt = 0; rt < 2; ++rt) {
        const float* ap = in + (size_t)(t0 + tg * 32 + rt * 16 + l15) * HID + d * ED + lk8 * 8;
        #pragma unroll
        for (int ks = 0; ks < 4; ++ks) {
            float4 v0 = *(const float4*)(ap + ks * 32);
            float4 v1 = *(const float4*)(ap + ks * 32 + 4);
            float vv[8] = {v0.x, v0.y, v0.z, v0.w, v1.x, v1.y, v1.z, v1.w};
            short8v hv, lv;
            #pragma unroll
            for (int j = 0; j < 8; ++j) {
                unsigned short hb = bf16h(vv[j]);
                hv[j] = (short)hb;
                lv[j] = (short)bf16h(vv[j] - bf16f(hb));
            }
            ahf[rt][ks] = hv; alf[rt][ks] = lv;
        }
    }

    float b1[2][4], b2[2][4];
    int   bk[2][4];
    #pragma unroll
    for (int rt = 0; rt < 2; ++rt)
        #pragma unroll
        for (int r = 0; r < 4; ++r) { b1[rt][r] = 3.0e38f; b2[rt][r] = 3.0e38f; bk[rt][r] = 0; }

    char* lb = (char*)Bst;
    const int ldsW = wid * 1024;            // wave-uniform lane-block base

    // source chunk pointers: q4 = 2*half + arr (hi/lo); tile stride = 2048 ushorts
    const unsigned short* sp[4];
    #pragma unroll
    for (int q4 = 0; q4 < 4; ++q4)
        sp[q4] = (q4 & 1 ? btl2 : bth2) +
                 ((size_t)(d * 256 + (q4 >> 1) * 128) * 256 + tid) * 8;

    // prologue: stage tile 0 into buf0
    #pragma unroll
    for (int q4 = 0; q4 < 4; ++q4)
        GLDS16(sp[q4], lb + q4 * 4096 + ldsW);
    __syncthreads();

    for (int s = 0; s < 128; ++s) {
        const int p = s & 1;
        char* cur = lb + p * 16384;
        if (s < 127) {                       // STAGE next tile first (overlaps MFMA)
            char* nxt = lb + (p ^ 1) * 16384;
            #pragma unroll
            for (int q4 = 0; q4 < 4; ++q4)
                GLDS16(sp[q4] + (size_t)(s + 1) * 2048, nxt + q4 * 4096 + ldsW);
        }
        const int codev = h * 2048 + s * 16 + l15;
        const float e2v = e2g[d * KCODES + codev];

        float4v acc[2] = {{0,0,0,0},{0,0,0,0}};
        #pragma unroll
        for (int ks = 0; ks < 4; ++ks) {
            const int gswz = (ks * 4 + lk8) ^ l15;
            short8v bh = *(const short8v*)(cur + (2 * h) * 4096 + l15 * 256 + gswz * 16);
            short8v bl = *(const short8v*)(cur + (2 * h + 1) * 4096 + l15 * 256 + gswz * 16);
            acc[0] = __builtin_amdgcn_mfma_f32_16x16x32_bf16(ahf[0][ks], bh, acc[0], 0, 0, 0);
            acc[1] = __builtin_amdgcn_mfma_f32_16x16x32_bf16(ahf[1][ks], bh, acc[1], 0, 0, 0);
            acc[0] = __builtin_amdgcn_mfma_f32_16x16x32_bf16(alf[0][ks], bh, acc[0], 0, 0, 0);
            acc[1] = __builtin_amdgcn_mfma_f32_16x16x32_bf16(alf[1][ks], bh, acc[1], 0, 0, 0);
            acc[0] = __builtin_amdgcn_mfma_f32_16x16x32_bf16(ahf[0][ks], bl, acc[0], 0, 0, 0);
            acc[1] = __builtin_amdgcn_mfma_f32_16x16x32_bf16(ahf[1][ks], bl, acc[1], 0, 0, 0);
        }
        #pragma unroll
        for (int rt = 0; rt < 2; ++rt) {
            #pragma unroll
            for (int r = 0; r < 4; ++r) {
                float dv = __fmaf_rn(-2.0f, acc[rt][r], e2v);
                if (dv < b1[rt][r]) { b2[rt][r] = b1[rt][r]; b1[rt][r] = dv; bk[rt][r] = codev; }
                else if (dv < b2[rt][r]) { b2[rt][r] = dv; }
            }
        }
        asm volatile("s_waitcnt vmcnt(0)" ::: "memory");   // next tile landed
        __builtin_amdgcn_s_barrier();                      // all waves done w/ cur
    }

    // butterfly merge over the 16 column-lanes, tie -> lowest k
    #pragma unroll
    for (int m = 1; m <= 8; m <<= 1) {
        #pragma unroll
        for (int rt = 0; rt < 2; ++rt) {
            #pragma unroll
            for (int r = 0; r < 4; ++r) {
                float od = __shfl_xor(b1[rt][r], m, 64);
                float o2 = __shfl_xor(b2[rt][r], m, 64);
                int   ok = __shfl_xor(bk[rt][r], m, 64);
                if (od < b1[rt][r] || (od == b1[rt][r] && ok < bk[rt][r])) {
                    b2[rt][r] = fminf(b1[rt][r], o2);
                    b1[rt][r] = od;
                    bk[rt][r] = ok;
                } else {
                    b2[rt][r] = fminf(b2[rt][r], od);
                }
            }
        }
    }
    __syncthreads();    // Bst no longer needed; overlay merge arrays
    float* mb1 = (float*)Bst;         // [128]
    float* mb2 = mb1 + 128;           // [128]
    int*   mbk = (int*)(mb1 + 256);   // [128]
    if (l15 == 0) {
        #pragma unroll
        for (int rt = 0; rt < 2; ++rt) {
            #pragma unroll
            for (int r = 0; r < 4; ++r) {
                int tok = tg * 32 + rt * 16 + lk8 * 4 + r;   // 0..63
                mb1[h * 64 + tok] = b1[rt][r];
                mb2[h * 64 + tok] = b2[rt][r];
                mbk[h * 64 + tok] = bk[rt][r];
            }
        }
    }
    __syncthreads();
    if (tid < 64) {
        float a1 = mb1[tid],      a2 = mb2[tid];      int ak = mbk[tid];
        float c1 = mb1[64 + tid], c2 = mb2[64 + tid]; int ck = mbk[64 + tid];
        float B1, B2; int K;
        if (a1 < c1 || (a1 == c1 && ak < ck)) { B1 = a1; K = ak; B2 = fminf(a2, c1); }
        else                                  { B1 = c1; K = ck; B2 = fminf(c2, a1); }
        int tok = d * NTOK + t0 + tid;
        lat[tok] = K;
        if (B2 - B1 < MARGIN) {
            int slot = atomicAdd(flag_cnt, 1);
            if (slot < FLAG_CAP) flag_list[slot] = tok;
        }
    }
}

// Exact repair, bit-matching verified ref semantics (x2 computed in-kernel).
__global__ __launch_bounds__(256) void repair_kernel(const float* __restrict__ in,
        const float* __restrict__ emb, const float* __restrict__ e2g,
        const int* __restrict__ flag_cnt, const int* __restrict__ flag_list,
        int* __restrict__ lat) {
    __shared__ float xs[ED];
    __shared__ float rd[256];
    __shared__ int   rk[256];
    int n = *flag_cnt;
    if (n > FLAG_CAP) n = FLAG_CAP;
    for (int idx = blockIdx.x; idx < n; idx += gridDim.x) {
        int tok = flag_list[idx];
        int d = tok >> 14;               // tok = d*NTOK + t
        int t = tok & (NTOK - 1);
        __syncthreads();
        if (threadIdx.x < ED) xs[threadIdx.x] = in[(size_t)t * HID + d * ED + threadIdx.x];
        __syncthreads();
        float x2v = 0.f;                 // strict serial, matches ref
        for (int e = 0; e < ED; ++e) x2v = __fadd_rn(x2v, __fmul_rn(xs[e], xs[e]));
        const float* __restrict__ embd = emb + (size_t)d * ED * KCODES;
        float bd = 3.0e38f; int bkk = 0;
        for (int j = 0; j < 16; ++j) {
            int k = threadIdx.x + j * 256;      // ascending k per thread
            float acc = 0.f;
            #pragma unroll 16
            for (int e = 0; e < ED; ++e)
                acc = __fmaf_rn(xs[e], embd[(size_t)e * KCODES + k], acc);
            float dist = __fsub_rn(__fadd_rn(x2v, e2g[d * KCODES + k]),
                                   __fmul_rn(2.0f, acc));
            if (dist < bd) { bd = dist; bkk = k; }
        }
        rd[threadIdx.x] = bd; rk[threadIdx.x] = bkk;
        __syncthreads();
        for (int w = 128; w > 0; w >>= 1) {
            if (threadIdx.x < w) {
                float od = rd[threadIdx.x + w]; int ok = rk[threadIdx.x + w];
                if (od < rd[threadIdx.x] || (od == rd[threadIdx.x] && ok < rk[threadIdx.x])) {
                    rd[threadIdx.x] = od; rk[threadIdx.x] = ok;
                }
            }
            __syncthreads();
        }
        if (threadIdx.x == 0) lat[tok] = rk[0];
    }
}

// out[n] = fl(fl(x + e) - x), n = (d,e,t); per-block partials of (x - e)^2
__global__ __launch_bounds__(256) void gather_kernel(const float* __restrict__ in,
        const float* __restrict__ emb, const int* __restrict__ lat,
        float* __restrict__ out, float* __restrict__ partial) {
    int tid  = threadIdx.x;
    int base = blockIdx.x * 1024 + tid * 4;
    int d = base >> 21;
    int e = (base >> 14) & 127;
    int t = base & (NTOK - 1);
    const int4 kk = *(const int4*)(lat + d * NTOK + t);
    const float* __restrict__ row = emb + ((size_t)(d * ED + e)) * KCODES;
    float enc[4];
    enc[0] = row[kk.x]; enc[1] = row[kk.y]; enc[2] = row[kk.z]; enc[3] = row[kk.w];
    const float4 x = *(const float4*)(in + base);
    const float xv[4] = {x.x, x.y, x.z, x.w};
    float4 ov; float* o = (float*)&ov;
    float s = 0.f;
    #pragma unroll
    for (int i = 0; i < 4; ++i) {
        o[i] = __fsub_rn(__fadd_rn(xv[i], enc[i]), xv[i]);
        float df = xv[i] - enc[i];
        s = __fmaf_rn(df, df, s);
    }
    *(float4*)(out + base) = ov;
    #pragma unroll
    for (int off = 32; off > 0; off >>= 1) s += __shfl_down(s, off, 64);
    __shared__ float wsum[4];
    if ((tid & 63) == 0) wsum[tid >> 6] = s;
    __syncthreads();
    if (tid == 0) partial[blockIdx.x] = wsum[0] + wsum[1] + wsum[2] + wsum[3];
}

__global__ __launch_bounds__(256) void finalize_kernel(const float* __restrict__ partial,
                                                       float* __restrict__ out_tail) {
    __shared__ double sh[256];
    double s = 0.0;
    for (int i = threadIdx.x; i < 8192; i += 256) s += (double)partial[i];
    sh[threadIdx.x] = s;
    __syncthreads();
    for (int w = 128; w > 0; w >>= 1) {
        if (threadIdx.x < w) sh[threadIdx.x] += sh[threadIdx.x + w];
        __syncthreads();
    }
    if (threadIdx.x == 0) {
        double mean = sh[0] / (double)NTOT;
        out_tail[0] = (float)(0.25 * mean);   // loss
        out_tail[1] = (float)mean;            // commit_loss
        ((int*)out_tail)[2] = 0;              // kl (int32 0 == fp32 0.0 bits)
    }
}

extern "C" void kernel_launch(void* const* d_in, const int* in_sizes, int n_in,
                              void* d_out, int out_size, void* d_ws, size_t ws_size,
                              hipStream_t stream) {
    const float* in  = (const float*)d_in[0];
    const float* emb = (const float*)d_in[1];
    float* out = (float*)d_out;
    char* ws = (char*)d_ws;

    int*   lat       = (int*)ws;                         // 256 KB
    float* e2g       = (float*)(ws + 262144);            // 64 KB
    float* partial   = (float*)(ws + 327680);            // 32 KB
    int*   flag_cnt  = (int*)(ws + 360448);              // 4 B
    int*   flag_list = (int*)(ws + 360452);              // 64 KB
    unsigned short* bth2 = (unsigned short*)(ws + (1 << 20));             // 4 MB
    unsigned short* btl2 = (unsigned short*)(ws + (1 << 20) + 4194304);   // 4 MB

    hipLaunchKernelGGL(e2split_kernel, dim3(256, 4), dim3(256), 0, stream,
                       emb, e2g, bth2, btl2, flag_cnt);
    hipLaunchKernelGGL(argmin_mfma_kernel, dim3(1024), dim3(256), 0, stream,
                       in, bth2, btl2, e2g, lat, flag_cnt, flag_list);
    hipLaunchKernelGGL(repair_kernel, dim3(64), dim3(256), 0, stream,
                       in, emb, e2g, flag_cnt, flag_list, lat);
    hipLaunchKernelGGL(gather_kernel, dim3(NTOT / 1024), dim3(256), 0, stream,
                       in, emb, lat, out, partial);
    hipLaunchKernelGGL(finalize_kernel, dim3(1), dim3(256), 0, stream, partial, out + NTOT);
}

// Round 18
// 273.618 us; speedup vs baseline: 1.2641x; 1.2426x over previous
//
#include <hip/hip_runtime.h>

#define ND 4
#define ED 128
#define KCODES 4096
#define NTOK 16384          // B*S
#define HID 512
#define NTOT (ND*ED*NTOK)   // 8388608

#define MARGIN 2.0e-3f
#define FLAG_CAP 16384

typedef __attribute__((ext_vector_type(8))) short short8v;
typedef __attribute__((ext_vector_type(4))) float float4v;

#define GLDS16(g, l) __builtin_amdgcn_global_load_lds( \
    (const __attribute__((address_space(1))) unsigned int*)(g), \
    (__attribute__((address_space(3))) unsigned int*)(l), 16, 0, 0)

__device__ __forceinline__ unsigned short bf16h(float x) {
    unsigned u = __float_as_uint(x);
    return (unsigned short)((u + 0x7fffu + ((u >> 16) & 1u)) >> 16);
}
__device__ __forceinline__ float bf16f(unsigned short h) {
    return __uint_as_float(((unsigned)h) << 16);
}

// Fused: exact e2 (serial asc-e mul/add, bit-matches ref) + B hi/lo split into
// one linear 8KB record per (d,16-code tile) == the LDS image GLDS will build.
// Record layout (bytes): arr(2)*4096 + code(16)*256 + kpos(16)*16 + j(8)*2,
// kpos = (logical k-octet) ^ code  (bank swizzle baked in).
__global__ __launch_bounds__(256) void e2split_kernel(const float* __restrict__ emb,
        float* __restrict__ e2g, unsigned short* __restrict__ bfrag,
        int* __restrict__ flag_cnt) {
    __shared__ float Tf[128][17];
    const int tile = blockIdx.x;      // 16-code tile
    const int d    = blockIdx.y;
    const int tid  = threadIdx.x;
    const int k0   = tile * 16;
    if (tile == 0 && d == 0 && tid == 0) *flag_cnt = 0;
    {
        int e = tid >> 1, half = tid & 1;
        const float* src = emb + ((size_t)d * ED + e) * KCODES + k0 + half * 8;
        float4 v0 = *(const float4*)(src);
        float4 v1 = *(const float4*)(src + 4);
        float* dst = &Tf[e][half * 8];
        dst[0] = v0.x; dst[1] = v0.y; dst[2] = v0.z; dst[3] = v0.w;
        dst[4] = v1.x; dst[5] = v1.y; dst[6] = v1.z; dst[7] = v1.w;
    }
    __syncthreads();
    if (tid < 16) {
        float s = 0.f;
        for (int e = 0; e < ED; ++e) {
            float v = Tf[e][tid];
            s = __fadd_rn(s, __fmul_rn(v, v));
        }
        e2g[d * KCODES + k0 + tid] = s;
    }
    #pragma unroll
    for (int q = 0; q < 2; ++q) {
        int c    = q * 256 + tid;          // 0..511 chunks of 16B
        int arr  = c >> 8;
        int rem  = c & 255;
        int code = rem >> 4;
        int kpos = rem & 15;
        int e0   = (kpos ^ code) * 8;
        short8v v;
        #pragma unroll
        for (int j = 0; j < 8; ++j) {
            float x = Tf[e0 + j][code];
            unsigned short hb = bf16h(x);
            v[j] = arr ? (short)bf16h(x - bf16f(hb)) : (short)hb;
        }
        size_t idx = ((size_t)(d * 256 + tile)) * 4096 + arr * 2048 + code * 128 + kpos * 8;
        *(short8v*)(bfrag + idx) = v;
    }
}

// MFMA bf16x3 argmin. 4 waves = 4 token-groups (32 tok each), all codes/wave.
// Counted-vmcnt pipeline: stage(s+2) -> compute(s) -> vmcnt(2) -> s_barrier.
// u32-packed argmin (dists biased positive), exact u64 butterfly w/ code tiebreak.
__global__ __launch_bounds__(256, 2)
void argmin_mfma_kernel(const float* __restrict__ in,
        const unsigned short* __restrict__ bfrag, const float* __restrict__ e2g,
        int* __restrict__ lat, int* __restrict__ flag_cnt, int* __restrict__ flag_list) {
    __shared__ __align__(16) char LB[49152];   // 4 x 8KB staging bufs + 16KB e2p

    // XCD-aware decode: blocks on one XCD share one d
    const int l   = blockIdx.x;           // 0..511
    const int r8  = l & 7;
    const int d   = r8 >> 1;
    const int tI  = 2 * (l >> 3) + (r8 & 1);   // 0..127
    const int t0  = tI * 128;

    const int tid  = threadIdx.x;
    const int w    = tid >> 6;
    const int lane = tid & 63;
    const int l15  = lane & 15;
    const int lk8  = lane >> 4;     // 0..3

    float* e2p = (float*)(LB + 32768);
    #pragma unroll
    for (int i = 0; i < 16; ++i) {
        int idx = i * 256 + tid;
        e2p[idx] = e2g[d * KCODES + idx] + 512.0f;   // bias -> positive dists
    }

    // A fragments: rows t0 + w*32 + rt*16 + l15, e = ks*32 + lk8*8 + j
    short8v ahf[2][4], alf[2][4];
    #pragma unroll
    for (int rt = 0; rt < 2; ++rt) {
        const float* ap = in + (size_t)(t0 + w * 32 + rt * 16 + l15) * HID + d * ED + lk8 * 8;
        #pragma unroll
        for (int ks = 0; ks < 4; ++ks) {
            float4 v0 = *(const float4*)(ap + ks * 32);
            float4 v1 = *(const float4*)(ap + ks * 32 + 4);
            float vv[8] = {v0.x, v0.y, v0.z, v0.w, v1.x, v1.y, v1.z, v1.w};
            short8v hv, lv;
            #pragma unroll
            for (int j = 0; j < 8; ++j) {
                unsigned short hb = bf16h(vv[j]);
                hv[j] = (short)hb;
                lv[j] = (short)bf16h(vv[j] - bf16f(hb));
            }
            ahf[rt][ks] = hv; alf[rt][ks] = lv;
        }
    }

    // per-lane frag byte-offsets within a buffer (swizzle-matched to bsplit)
    int fo[4];
    #pragma unroll
    for (int ks = 0; ks < 4; ++ks)
        fo[ks] = l15 * 256 + (((ks * 4 + lk8) ^ l15) * 16);

    // staging source (per-lane): record base + tid*16
    const char* sb = (const char*)bfrag + ((size_t)(d * 256)) * 8192 + tid * 16;

    // prologue: stage tiles 0,1
    #pragma unroll
    for (int t = 0; t < 2; ++t) {
        GLDS16(sb + t * 8192,        LB + t * 8192 + w * 1024);
        GLDS16(sb + t * 8192 + 4096, LB + t * 8192 + 4096 + w * 1024);
    }
    __syncthreads();    // drains vmcnt+lgkm once

    unsigned m1[2][4], m2[2][4];
    int bk[2][4];
    #pragma unroll
    for (int rt = 0; rt < 2; ++rt)
        #pragma unroll
        for (int r = 0; r < 4; ++r) { m1[rt][r] = 0xFFFFFFFFu; m2[rt][r] = 0xFFFFFFFFu; bk[rt][r] = 0; }

    #pragma unroll 4
    for (int s = 0; s < 256; ++s) {
        if (s < 254) {      // stage tile s+2 (stays in flight across barriers)
            const char* sp = sb + (size_t)(s + 2) * 8192;
            char* dp = LB + ((s + 2) & 3) * 8192 + w * 1024;
            GLDS16(sp,        dp);
            GLDS16(sp + 4096, dp + 4096);
        }
        const char* cur = LB + (s & 3) * 8192;
        const float e2v = e2p[s * 16 + l15];

        float4v aP[2] = {{0,0,0,0},{0,0,0,0}};
        float4v aQ[2] = {{0,0,0,0},{0,0,0,0}};
        #pragma unroll
        for (int ks = 0; ks < 4; ++ks) {
            short8v bh = *(const short8v*)(cur + fo[ks]);
            short8v bl = *(const short8v*)(cur + 4096 + fo[ks]);
            aP[0] = __builtin_amdgcn_mfma_f32_16x16x32_bf16(ahf[0][ks], bh, aP[0], 0, 0, 0);
            aP[1] = __builtin_amdgcn_mfma_f32_16x16x32_bf16(ahf[1][ks], bh, aP[1], 0, 0, 0);
            aP[0] = __builtin_amdgcn_mfma_f32_16x16x32_bf16(alf[0][ks], bh, aP[0], 0, 0, 0);
            aP[1] = __builtin_amdgcn_mfma_f32_16x16x32_bf16(alf[1][ks], bh, aP[1], 0, 0, 0);
            aQ[0] = __builtin_amdgcn_mfma_f32_16x16x32_bf16(ahf[0][ks], bl, aQ[0], 0, 0, 0);
            aQ[1] = __builtin_amdgcn_mfma_f32_16x16x32_bf16(ahf[1][ks], bl, aQ[1], 0, 0, 0);
        }
        #pragma unroll
        for (int rt = 0; rt < 2; ++rt) {
            #pragma unroll
            for (int r = 0; r < 4; ++r) {
                float cs = aP[rt][r] + aQ[rt][r];
                float dv = __fmaf_rn(-2.0f, cs, e2v);          // positive (bias)
                unsigned kk = __float_as_uint(dv);
                unsigned mo = m1[rt][r];
                unsigned mx = mo > kk ? mo : kk;
                m2[rt][r] = m2[rt][r] < mx ? m2[rt][r] : mx;
                if (kk < mo) { bk[rt][r] = s; m1[rt][r] = kk; }
            }
        }
        if (s < 254)        asm volatile("s_waitcnt vmcnt(2)" ::: "memory");
        else if (s == 254)  asm volatile("s_waitcnt vmcnt(0)" ::: "memory");
        __builtin_amdgcn_s_barrier();
    }

    // exact u64 butterfly over the 16 code-lanes; low bits carry code (tiebreak)
    #pragma unroll
    for (int rt = 0; rt < 2; ++rt) {
        #pragma unroll
        for (int r = 0; r < 4; ++r) {
            unsigned long long key = ((unsigned long long)m1[rt][r] << 32) |
                                     (unsigned)(bk[rt][r] * 16 + l15);
            unsigned mm2 = m2[rt][r];
            #pragma unroll
            for (int m = 1; m <= 8; m <<= 1) {
                unsigned long long ok = __shfl_xor(key, m, 64);
                unsigned om = __shfl_xor(mm2, m, 64);
                unsigned loser = (ok < key) ? (unsigned)(key >> 32) : (unsigned)(ok >> 32);
                key = ok < key ? ok : key;
                unsigned t2 = om < loser ? om : loser;
                mm2 = mm2 < t2 ? mm2 : t2;
            }
            if (l15 == 0) {
                int code = (int)(key & 0xFFFFu);
                int tok = d * NTOK + t0 + w * 32 + rt * 16 + lk8 * 4 + r;
                lat[tok] = code;
                float gap = __uint_as_float(mm2) - __uint_as_float((unsigned)(key >> 32));
                if (gap < MARGIN) {
                    int slot = atomicAdd(flag_cnt, 1);
                    if (slot < FLAG_CAP) flag_list[slot] = tok;
                }
            }
        }
    }
}

// Exact repair, bit-matching verified ref semantics (x2 computed in-kernel).
__global__ __launch_bounds__(256) void repair_kernel(const float* __restrict__ in,
        const float* __restrict__ emb, const float* __restrict__ e2g,
        const int* __restrict__ flag_cnt, const int* __restrict__ flag_list,
        int* __restrict__ lat) {
    __shared__ float xs[ED];
    __shared__ float rd[256];
    __shared__ int   rk[256];
    int n = *flag_cnt;
    if (n > FLAG_CAP) n = FLAG_CAP;
    for (int idx = blockIdx.x; idx < n; idx += gridDim.x) {
        int tok = flag_list[idx];
        int d = tok >> 14;               // tok = d*NTOK + t
        int t = tok & (NTOK - 1);
        __syncthreads();
        if (threadIdx.x < ED) xs[threadIdx.x] = in[(size_t)t * HID + d * ED + threadIdx.x];
        __syncthreads();
        float x2v = 0.f;                 // strict serial, matches ref
        for (int e = 0; e < ED; ++e) x2v = __fadd_rn(x2v, __fmul_rn(xs[e], xs[e]));
        const float* __restrict__ embd = emb + (size_t)d * ED * KCODES;
        float bd = 3.0e38f; int bkk = 0;
        for (int j = 0; j < 16; ++j) {
            int k = threadIdx.x + j * 256;      // ascending k per thread
            float acc = 0.f;
            #pragma unroll 16
            for (int e = 0; e < ED; ++e)
                acc = __fmaf_rn(xs[e], embd[(size_t)e * KCODES + k], acc);
            float dist = __fsub_rn(__fadd_rn(x2v, e2g[d * KCODES + k]),
                                   __fmul_rn(2.0f, acc));
            if (dist < bd) { bd = dist; bkk = k; }
        }
        rd[threadIdx.x] = bd; rk[threadIdx.x] = bkk;
        __syncthreads();
        for (int w = 128; w > 0; w >>= 1) {
            if (threadIdx.x < w) {
                float od = rd[threadIdx.x + w]; int ok = rk[threadIdx.x + w];
                if (od < rd[threadIdx.x] || (od == rd[threadIdx.x] && ok < rk[threadIdx.x])) {
                    rd[threadIdx.x] = od; rk[threadIdx.x] = ok;
                }
            }
            __syncthreads();
        }
        if (threadIdx.x == 0) lat[tok] = rk[0];
    }
}

// out[n] = fl(fl(x + e) - x), n = (d,e,t); per-block partials of (x - e)^2
__global__ __launch_bounds__(256) void gather_kernel(const float* __restrict__ in,
        const float* __restrict__ emb, const int* __restrict__ lat,
        float* __restrict__ out, float* __restrict__ partial) {
    int tid  = threadIdx.x;
    int base = blockIdx.x * 1024 + tid * 4;
    int d = base >> 21;
    int e = (base >> 14) & 127;
    int t = base & (NTOK - 1);
    const int4 kk = *(const int4*)(lat + d * NTOK + t);
    const float* __restrict__ row = emb + ((size_t)(d * ED + e)) * KCODES;
    float enc[4];
    enc[0] = row[kk.x]; enc[1] = row[kk.y]; enc[2] = row[kk.z]; enc[3] = row[kk.w];
    const float4 x = *(const float4*)(in + base);
    const float xv[4] = {x.x, x.y, x.z, x.w};
    float4 ov; float* o = (float*)&ov;
    float s = 0.f;
    #pragma unroll
    for (int i = 0; i < 4; ++i) {
        o[i] = __fsub_rn(__fadd_rn(xv[i], enc[i]), xv[i]);
        float df = xv[i] - enc[i];
        s = __fmaf_rn(df, df, s);
    }
    *(float4*)(out + base) = ov;
    #pragma unroll
    for (int off = 32; off > 0; off >>= 1) s += __shfl_down(s, off, 64);
    __shared__ float wsum[4];
    if ((tid & 63) == 0) wsum[tid >> 6] = s;
    __syncthreads();
    if (tid == 0) partial[blockIdx.x] = wsum[0] + wsum[1] + wsum[2] + wsum[3];
}

__global__ __launch_bounds__(256) void finalize_kernel(const float* __restrict__ partial,
                                                       float* __restrict__ out_tail) {
    __shared__ double sh[256];
    double s = 0.0;
    for (int i = threadIdx.x; i < 8192; i += 256) s += (double)partial[i];
    sh[threadIdx.x] = s;
    __syncthreads();
    for (int w = 128; w > 0; w >>= 1) {
        if (threadIdx.x < w) sh[threadIdx.x] += sh[threadIdx.x + w];
        __syncthreads();
    }
    if (threadIdx.x == 0) {
        double mean = sh[0] / (double)NTOT;
        out_tail[0] = (float)(0.25 * mean);   // loss
        out_tail[1] = (float)mean;            // commit_loss
        ((int*)out_tail)[2] = 0;              // kl (int32 0 == fp32 0.0 bits)
    }
}

extern "C" void kernel_launch(void* const* d_in, const int* in_sizes, int n_in,
                              void* d_out, int out_size, void* d_ws, size_t ws_size,
                              hipStream_t stream) {
    const float* in  = (const float*)d_in[0];
    const float* emb = (const float*)d_in[1];
    float* out = (float*)d_out;
    char* ws = (char*)d_ws;

    int*   lat       = (int*)ws;                         // 256 KB
    float* e2g       = (float*)(ws + 262144);            // 64 KB
    float* partial   = (float*)(ws + 327680);            // 32 KB
    int*   flag_cnt  = (int*)(ws + 360448);              // 4 B
    int*   flag_list = (int*)(ws + 360452);              // 64 KB
    unsigned short* bfrag = (unsigned short*)(ws + (1 << 20));   // 8 MB

    hipLaunchKernelGGL(e2split_kernel, dim3(256, 4), dim3(256), 0, stream,
                       emb, e2g, bfrag, flag_cnt);
    hipLaunchKernelGGL(argmin_mfma_kernel, dim3(512), dim3(256), 0, stream,
                       in, bfrag, e2g, lat, flag_cnt, flag_list);
    hipLaunchKernelGGL(repair_kernel, dim3(64), dim3(256), 0, stream,
                       in, emb, e2g, flag_cnt, flag_list, lat);
    hipLaunchKernelGGL(gather_kernel, dim3(NTOT / 1024), dim3(256), 0, stream,
                       in, emb, lat, out, partial);
    hipLaunchKernelGGL(finalize_kernel, dim3(1), dim3(256), 0, stream, partial, out + NTOT);
}